// Round 19
// baseline (2417.400 us; speedup 1.0000x reference)
//
#include <hip/hip_runtime.h>
#include <hip/hip_bf16.h>

// STDP IF-neuron network, T=50 sequential steps. Pair-split persistent v16.
// x_seq [50,256,1024] f32, weight [2048,1024] f32 -> spike_trace [256,2048] f32.
//
// Base = r18 (706us: 128 blocks x 16 waves, W fp32 master in LDS, frag-order
// bf16 fwd stream (2-deep pipelined, boundary prefetch) + exact-i8 wupd).
//
// v16: use all 256 CUs. Pair (slab = bid&127, half = bid>>7) splits the
// BATCH: each block runs fwd/IF for its 128 b-rows (fwd stream 1MB ->
// 0.5MB/step; k-split keeps all 16 waves busy: waves w and w+8 share
// b-tile w, 16 k-chunks each, reduced via LDS), exchanges 2KB of s-frags
// through global (one flag handshake/step; same-XCD pair; r11-proven
// mechanism -- r11's cost was the 32KB W export, eliminated here), then
// REDUNDANTLY computes the identical full wupd + W update (both blocks'
// W stay bit-identical; zero W traffic). Per-CU: 1.5 -> 1.0 MB/step.
// Numerics: only change is fwd k-summation order (acc_lo+acc_hi) -- same
// fp32-reorder class that has held absmax <= 1.0 all session.

#define T_STEPS 50
#define BATCH   256
#define DIM     1024
#define HID     2048
#define HT      16
#define LR_OVER_B (0.005f / 256.0f)

// LDS: wfs 64KB | whF 32KB | wlF 32KB | slQ 4KB | red 8KB
#define SMEM_BYTES (65536 + 32768 + 32768 + 4096 + 8192)

typedef __attribute__((ext_vector_type(8))) short short8v;
typedef __attribute__((ext_vector_type(4))) float f32x4;
typedef __attribute__((ext_vector_type(4))) int   i32x4;

static __device__ __forceinline__ ushort f32_to_bf16u(float f) {
    __hip_bfloat16 h = __float2bfloat16(f);
    return __builtin_bit_cast(unsigned short, h);
}
static __device__ __forceinline__ float bf16u_to_f32(ushort u) {
    __hip_bfloat16 h = __builtin_bit_cast(__hip_bfloat16, u);
    return __bfloat162float(h);
}

#define MFMA_B16 __builtin_amdgcn_mfma_f32_16x16x32_bf16
#define MFMA_I8  __builtin_amdgcn_mfma_i32_16x16x64_i8

// ---------------- prep A: fwd fragment packing (r10, unchanged) -----------
// XF[t][bt=0..15][c=0..31][h=0..1][lane=0..63][8] ushorts.
__global__ __launch_bounds__(256) void prep_fwd(
    const float* __restrict__ x, ushort* __restrict__ XF)
{
    __shared__ float xs[16 * 1024];
    const int t  = blockIdx.x >> 4;
    const int bt = blockIdx.x & 15;
    const float* xrow = x + ((size_t)t * BATCH + bt * 16) * DIM;
    for (int i = threadIdx.x; i < 16 * 1024 / 4; i += 256)
        ((float4*)xs)[i] = ((const float4*)xrow)[i];
    __syncthreads();

    ushort* outb = XF + ((size_t)t * 16 + bt) * (32 * 2 * 512);
    for (int item = threadIdx.x; item < 32 * 64; item += 256) {
        const int c = item >> 6;
        const int l = item & 63;
        const int row = l & 15;
        const int col = c * 32 + (l >> 4) * 8;
        short8v hv, lv;
#pragma unroll
        for (int j = 0; j < 8; ++j) {
            float v = xs[row * 1024 + col + j];
            ushort h = f32_to_bf16u(v);
            hv[j] = (short)h;
            lv[j] = (short)f32_to_bf16u(v - bf16u_to_f32(h));
        }
        *(short8v*)(outb + ((size_t)c * 2 + 0) * 512 + l * 8) = hv;
        *(short8v*)(outb + ((size_t)c * 2 + 1) * 512 + l * 8) = lv;
    }
}

// ---------------- prep B: wupd i8 fixed-point fragment packing ------------
// XQ[t][dt=0..63][c=0..3][plane hi/lo][lane=0..63][16] bytes.
__global__ __launch_bounds__(256) void prep_xq(
    const float* __restrict__ x, unsigned char* __restrict__ XQ)
{
    __shared__ ushort q14[256 * 16];
    const int t  = blockIdx.x >> 6;
    const int dt = blockIdx.x & 63;
    {
        const int b = threadIdx.x;
        const float* src = x + ((size_t)t * BATCH + b) * DIM + dt * 16;
#pragma unroll
        for (int k = 0; k < 16; ++k) {
            int u = (int)(src[k] * 16384.0f + 0.5f);
            q14[b * 16 + k] = (ushort)(u > 16383 ? 16383 : u);
        }
    }
    __syncthreads();

    unsigned char* outb = XQ + ((size_t)t * 64 + dt) * 8192;
    const int c = threadIdx.x >> 6;      // 0..3
    const int l = threadIdx.x & 63;
    unsigned char hi16[16], lo16[16];
#pragma unroll
    for (int jj = 0; jj < 16; ++jj) {
        const int b2 = c * 64 + (l >> 4) * 16 + jj;
        ushort v = q14[b2 * 16 + (l & 15)];
        hi16[jj] = (unsigned char)(v >> 7);
        lo16[jj] = (unsigned char)(v & 127);
    }
    *(i32x4*)(outb + c * 2048 + l * 16)        = *(i32x4*)hi16;
    *(i32x4*)(outb + c * 2048 + 1024 + l * 16) = *(i32x4*)lo16;
}

// ---------------- THE pair-split persistent kernel ------------------------
__global__ __launch_bounds__(1024, 1) void stdp_pair2(
    const ushort* __restrict__ XF, const unsigned char* __restrict__ XQ,
    const float* __restrict__ weight, float* __restrict__ out,
    unsigned char* __restrict__ sex,    // [256][2048] B: per-block s export
    unsigned* __restrict__ flagS)       // [256] (memset 0 per launch)
{
    extern __shared__ char smem[];
    float*  wfs = (float*)smem;               // [64 dt][64 lane][4] fp32 master
    ushort* whF = (ushort*)(smem + 65536);    // 32 chunks x 512 us (frag order)
    ushort* wlF = whF + 32 * 512;
    unsigned char* slQ = (unsigned char*)(smem + 131072);  // 4 chunks x 1KB
    float* red = (float*)(smem + 135168);     // [8 tile][64 lane][4] k-reduce

    const int bid  = blockIdx.x;
    const int slab = bid & 127;
    const int half = bid >> 7;
    const int tid  = threadIdx.x;
    const int lane = tid & 63;
    const int w    = tid >> 6;                // wave 0..15
    const int h0   = slab * HT;

    const int fr = lane & 15;                 // h index within slab
    const int rq = (lane >> 4) * 4;           // D-fragment row base

    const int btl   = w & 7;                  // local b-tile (shared w, w+8)
    const int kbase = (w >> 3) * 16;          // k-chunk range base

    unsigned char* sex_s = sex + (size_t)bid * 2048;
    const unsigned char* sex_p = sex + (size_t)(bid ^ 128) * 2048;
    unsigned* flag_s = &flagS[bid];
    unsigned* flag_p = &flagS[bid ^ 128];

    // ---- init whF/wlF: 32 chunks x 64 lane-slots (2 per thread) ----
    for (int i = tid; i < 32 * 64; i += 1024) {
        const int cc  = i >> 6;
        const int l   = i & 63;
        const int row = l & 15;
        const int col = cc * 32 + (l >> 4) * 8;
        const float* src = &weight[(size_t)(h0 + row) * DIM + col];
        short8v hv, lv;
#pragma unroll
        for (int j = 0; j < 8; ++j) {
            float v = src[j];
            ushort h = f32_to_bf16u(v);
            hv[j] = (short)h;
            lv[j] = (short)f32_to_bf16u(v - bf16u_to_f32(h));
        }
        *(short8v*)&whF[cc * 512 + l * 8] = hv;
        *(short8v*)&wlF[cc * 512 + l * 8] = lv;
    }
    // ---- init wfs: (dt, lane) owns h=lane&15, d=dt*16+((lane>>4)*4)+j ----
    for (int i = tid; i < 64 * 64; i += 1024) {
        const int dt = i >> 6;
        const int l  = i & 63;
        const int h  = l & 15;
        const int d  = dt * 16 + (l >> 4) * 4;
        *(float4*)&wfs[(size_t)i * 4] =
            *(const float4*)&weight[(size_t)(h0 + h) * DIM + d];
    }
    __syncthreads();

    const f32x4 z4 = {0.f, 0.f, 0.f, 0.f};
    const i32x4 zi = {0, 0, 0, 0};
    f32x4 vmem = z4;                          // valid in waves 0..7
    f32x4 trc  = z4;

    short8v GA[2][2], GB[2][2];               // fwd stream buffers
    i32x4 FH[4], FL[4];                       // wupd tile buffers

#define LDP(F, base, p) do { _Pragma("unroll") \
    for (int c_ = 0; c_ < 2; ++c_) { \
        const int cc_ = kbase + (p) * 2 + c_; \
        F[c_][0] = *(const short8v*)((base) + ((size_t)cc_ * 2 + 0) * 512); \
        F[c_][1] = *(const short8v*)((base) + ((size_t)cc_ * 2 + 1) * 512); } } while (0)

#define MFP(F, p) do { _Pragma("unroll") \
    for (int c_ = 0; c_ < 2; ++c_) { \
        const int cc_ = kbase + (p) * 2 + c_; \
        short8v bh_ = *(const short8v*)&whF[cc_ * 512 + lane * 8]; \
        short8v bl_ = *(const short8v*)&wlF[cc_ * 512 + lane * 8]; \
        acc = MFMA_B16(F[c_][0], bh_, acc, 0, 0, 0); \
        acc = MFMA_B16(F[c_][0], bl_, acc, 0, 0, 0); \
        acc = MFMA_B16(F[c_][1], bh_, acc, 0, 0, 0); } } while (0)

    // prologue: prefetch fwd pair 0 for t=0
    {
        const ushort* wb0 = XF + (size_t)(half * 8 + btl) * (32 * 2 * 512) + lane * 8;
        LDP(GA, wb0, 0);
    }

    for (int t = 0; t < T_STEPS; ++t) {
        const ushort* wbase = XF + (size_t)t * (16 * 32 * 2 * 512)
                            + (size_t)(half * 8 + btl) * (32 * 2 * 512) + lane * 8;

        // ============ fwd: mem = x @ W^T, k-split, 2-deep pipelined =======
        f32x4 acc = z4;
#pragma unroll 1
        for (int it = 0; it < 3; ++it) {
            LDP(GB, wbase, 2 * it + 1);
            MFP(GA, 2 * it);
            LDP(GA, wbase, 2 * it + 2);
            MFP(GB, 2 * it + 1);
        }
        LDP(GB, wbase, 7);
        MFP(GA, 6);
        MFP(GB, 7);

        // waves 8-15: export partial sums (k-chunks 16..31) to LDS
        if (w >= 8)
            *(f32x4*)&red[((w & 7) * 64 + lane) * 4] = acc;

        // ---- prefetch wupd tile-0 FH/FL (read-only; overlaps barrier) ----
        const unsigned char* xqt = XQ + (size_t)t * (64 * 8192);
        {
            const unsigned char* tb = xqt + (size_t)(w * 4) * 8192 + lane * 16;
#pragma unroll
            for (int c = 0; c < 4; ++c) {
                FH[c] = *(const i32x4*)(tb + c * 2048);
                FL[c] = *(const i32x4*)(tb + c * 2048 + 1024);
            }
        }

        __syncthreads();               // barrier A: red complete

        // ---- waves 0-7: reduce + IF update + s store (own b-half) ----
        if (w < 8) {
            f32x4 r = *(const f32x4*)&red[(w * 64 + lane) * 4];
            acc = acc + r;             // k-halves combined (order change vs r18)
            unsigned sword = 0;
#pragma unroll
            for (int j = 0; j < 4; ++j) {
                float nv = vmem[j] + acc[j];
                bool fire = (nv >= 1.0f);
                vmem[j] = fire ? 0.0f : nv;
                trc[j] += fire ? 1.0f : 0.0f;
                sword |= (fire ? 1u : 0u) << (8 * j);
            }
            const int soff = (w >> 2) * 1024 + ((w & 3) * 16 + fr) * 16 + rq;
            *(unsigned*)&slQ[half * 2048 + soff] = sword;
            if (t < T_STEPS - 1) {
                *(unsigned*)&sex_s[soff] = sword;
                __threadfence();       // publish sex at device scope
            }
        }

        if (t >= T_STEPS - 1) break;   // last step: no wupd/exchange

        __syncthreads();               // barrier B: s writes done

        // ---- flag handshake with partner block (same XCD) ----
        if (tid == 0) {
            __hip_atomic_store(flag_s, (unsigned)(t + 1),
                               __ATOMIC_RELEASE, __HIP_MEMORY_SCOPE_AGENT);
            while (__hip_atomic_load(flag_p, __ATOMIC_ACQUIRE,
                                     __HIP_MEMORY_SCOPE_AGENT) < (unsigned)(t + 1))
                __builtin_amdgcn_s_sleep(1);
        }
        __syncthreads();               // barrier C: partner s visible

        // ---- import partner s chunks (2 KB) into slQ ----
        if (tid < 128) {
            i32x4 v = *(const i32x4*)(sex_p + tid * 16);
            *(i32x4*)&slQ[(1 - half) * 2048 + tid * 16] = v;
        }
        __syncthreads();               // barrier D: slQ complete (all 4 chunks)

        // ============ wupd (i8): dw = s^T x exact int, W += lr/B*dw =======
        // all 16 waves; identical in both pair blocks -> W stays in sync.
#pragma unroll
        for (int q = 0; q < 4; ++q) {
            const int dt = w * 4 + q;
            i32x4 aH = zi, aL = zi;
#pragma unroll
            for (int c = 0; c < 4; ++c) {
                i32x4 sf = *(const i32x4*)&slQ[c * 1024 + lane * 16];
                aH = MFMA_I8(FH[c], sf, aH, 0, 0, 0);
                aL = MFMA_I8(FL[c], sf, aL, 0, 0, 0);
            }
            if (q < 3) {               // issue next tile's loads early
                const unsigned char* tb = xqt + (size_t)(dt + 1) * 8192 + lane * 16;
#pragma unroll
                for (int c = 0; c < 4; ++c) {
                    FH[c] = *(const i32x4*)(tb + c * 2048);
                    FL[c] = *(const i32x4*)(tb + c * 2048 + 1024);
                }
            }
            // ---- W master update (LDS, lane-linear) + re-split ----
            {
                float4* wp = (float4*)&wfs[((size_t)dt * 64 + lane) * 4];
                float4 wv = *wp;
                float* wvp = &wv.x;
                ushort4 hi4, lo4;
                ushort* hp = &hi4.x; ushort* lp = &lo4.x;
#pragma unroll
                for (int j = 0; j < 4; ++j) {
                    float du = (float)(aH[j] * 128 + aL[j]) * (1.0f / 16384.0f);
                    float nw = fmaf(LR_OVER_B, du, wvp[j]);
                    wvp[j] = nw;
                    ushort hb = f32_to_bf16u(nw);
                    hp[j] = hb;
                    lp[j] = f32_to_bf16u(nw - bf16u_to_f32(hb));
                }
                *wp = wv;
                const int l_w = fr | (((dt & 1) * 2 + (rq >> 3)) << 4);
                const int off = (dt >> 1) * 512 + l_w * 8 + (rq & 4);
                *(ushort4*)&whF[off] = hi4;
                *(ushort4*)&wlF[off] = lo4;
            }
            __builtin_amdgcn_sched_barrier(0);
        }

        // ---- prefetch fwd pair 0 for t+1 (GA dead here; read-only) ----
        {
            const ushort* wbn = XF + (size_t)(t + 1) * (16 * 32 * 2 * 512)
                              + (size_t)(half * 8 + btl) * (32 * 2 * 512) + lane * 8;
            LDP(GA, wbn, 0);
        }

        __syncthreads();               // barrier E: whF/wlF ready for next fwd
    }
#undef LDP
#undef MFP

    // ---- write trace to d_out [B,H]; waves 0-7 own b = half*128+w*16+rq+j
    if (w < 8) {
#pragma unroll
        for (int j = 0; j < 4; ++j) {
            const int b = half * 128 + w * 16 + rq + j;
            out[(size_t)b * HID + h0 + fr] = trc[j];
        }
    }
}

// ---------------- fallback fp32 kernels (round-0, small ws) ---------------
#define BK 16
__global__ __launch_bounds__(256) void stdp_fwd_if(
    const float* __restrict__ x, const float* __restrict__ w,
    float* __restrict__ v, float* __restrict__ s, float* __restrict__ trace)
{
    __shared__ float as[BK][64];
    __shared__ float bs[BK][64];
    const int tid = threadIdx.x;
    const int tx = tid & 15, ty = tid >> 4;
    const int b0 = blockIdx.y * 64, h0 = blockIdx.x * 64;
    const int row = tid >> 2, kq = (tid & 3) * 4;
    float acc[4][4] = {};
    for (int k0 = 0; k0 < DIM; k0 += BK) {
        float4 ga = *(const float4*)&x[(size_t)(b0 + row) * DIM + k0 + kq];
        float4 gb = *(const float4*)&w[(size_t)(h0 + row) * DIM + k0 + kq];
        __syncthreads();
        as[kq + 0][row] = ga.x; as[kq + 1][row] = ga.y;
        as[kq + 2][row] = ga.z; as[kq + 3][row] = ga.w;
        bs[kq + 0][row] = gb.x; bs[kq + 1][row] = gb.y;
        bs[kq + 2][row] = gb.z; bs[kq + 3][row] = gb.w;
        __syncthreads();
#pragma unroll
        for (int kk = 0; kk < BK; ++kk) {
            float4 af = *(const float4*)&as[kk][ty * 4];
            float4 bf = *(const float4*)&bs[kk][tx * 4];
            float av[4] = {af.x, af.y, af.z, af.w};
            float bv[4] = {bf.x, bf.y, bf.z, bf.w};
#pragma unroll
            for (int m = 0; m < 4; ++m)
#pragma unroll
                for (int n = 0; n < 4; ++n)
                    acc[m][n] = fmaf(av[m], bv[n], acc[m][n]);
        }
    }
#pragma unroll
    for (int m = 0; m < 4; ++m) {
        size_t idx = (size_t)(b0 + ty * 4 + m) * HID + h0 + tx * 4;
        float4 vv = *(float4*)&v[idx];
        float4 tr = *(float4*)&trace[idx];
        float4 sv;
        float* vvp = &vv.x; float* trp = &tr.x; float* svp = &sv.x;
#pragma unroll
        for (int n = 0; n < 4; ++n) {
            float nv = vvp[n] + acc[m][n];
            float sp = (nv >= 1.0f) ? 1.0f : 0.0f;
            vvp[n] = (nv >= 1.0f) ? 0.0f : nv;
            svp[n] = sp; trp[n] += sp;
        }
        *(float4*)&v[idx] = vv;
        *(float4*)&s[idx] = sv;
        *(float4*)&trace[idx] = tr;
    }
}

__global__ __launch_bounds__(256) void stdp_wupd(
    const float* __restrict__ x, const float* __restrict__ s,
    float* __restrict__ w)
{
    __shared__ float ss[BK][64];
    __shared__ float xs[BK][64];
    const int tid = threadIdx.x;
    const int tx = tid & 15, ty = tid >> 4;
    const int h0 = blockIdx.y * 64, d0 = blockIdx.x * 64;
    const int krow = tid >> 4, c4 = (tid & 15) * 4;
    float acc[4][4] = {};
    for (int bk0 = 0; bk0 < BATCH; bk0 += BK) {
        float4 gs = *(const float4*)&s[(size_t)(bk0 + krow) * HID + h0 + c4];
        float4 gx = *(const float4*)&x[(size_t)(bk0 + krow) * DIM + d0 + c4];
        __syncthreads();
        *(float4*)&ss[krow][c4] = gs;
        *(float4*)&xs[krow][c4] = gx;
        __syncthreads();
#pragma unroll
        for (int kk = 0; kk < BK; ++kk) {
            float4 af = *(const float4*)&ss[kk][ty * 4];
            float4 bf = *(const float4*)&xs[kk][tx * 4];
            float av[4] = {af.x, af.y, af.z, af.w};
            float bv[4] = {bf.x, bf.y, bf.z, bf.w};
#pragma unroll
            for (int m = 0; m < 4; ++m)
#pragma unroll
                for (int n = 0; n < 4; ++n)
                    acc[m][n] = fmaf(av[m], bv[n], acc[m][n]);
        }
    }
#pragma unroll
    for (int m = 0; m < 4; ++m) {
        size_t idx = (size_t)(h0 + ty * 4 + m) * DIM + d0 + tx * 4;
        float4 wv = *(float4*)&w[idx];
        wv.x = fmaf(LR_OVER_B, acc[m][0], wv.x);
        wv.y = fmaf(LR_OVER_B, acc[m][1], wv.y);
        wv.z = fmaf(LR_OVER_B, acc[m][2], wv.z);
        wv.w = fmaf(LR_OVER_B, acc[m][3], wv.w);
        *(float4*)&w[idx] = wv;
    }
}

extern "C" void kernel_launch(void* const* d_in, const int* in_sizes, int n_in,
                              void* d_out, int out_size, void* d_ws, size_t ws_size,
                              hipStream_t stream) {
    (void)in_sizes; (void)n_in;
    const float* x_seq  = (const float*)d_in[0];   // [T, B, D]
    const float* weight = (const float*)d_in[1];   // [H, D]
    float* out = (float*)d_out;                    // [B, H]

    const size_t WN = (size_t)HID * DIM;
    const size_t BH = (size_t)BATCH * HID;
    const size_t XN = (size_t)T_STEPS * BATCH * DIM;  // 13107200

    // ws: XF (4*XN B) | XQ (2*XN B) | sex (256*2048 B) | flagS (256 u32)
    const size_t need = 6 * XN + 256 * 2048 + 256 * 4;

    if (ws_size >= need) {
        ushort* XF = (ushort*)d_ws;                   // 2*XN ushorts
        unsigned char* XQ = (unsigned char*)(XF + 2 * XN);
        unsigned char* sexp = XQ + 2 * XN;
        unsigned* flagS = (unsigned*)(sexp + 256 * 2048);

        hipMemsetAsync(flagS, 0, 256 * 4, stream);    // replay-safe reset
        prep_fwd<<<T_STEPS * 16, 256, 0, stream>>>(x_seq, XF);
        prep_xq<<<T_STEPS * 64, 256, 0, stream>>>(x_seq, XQ);

        hipFuncSetAttribute(reinterpret_cast<const void*>(&stdp_pair2),
                            hipFuncAttributeMaxDynamicSharedMemorySize,
                            SMEM_BYTES);
        stdp_pair2<<<256, 1024, SMEM_BYTES, stream>>>(
            XF, XQ, weight, out, sexp, flagS);
    } else {
        // fallback: fp32 VALU path (needs ~12.6 MB)
        float* w = (float*)d_ws;
        float* v = w + WN;
        float* s = v + BH;
        hipMemcpyAsync(w, weight, WN * 4, hipMemcpyDeviceToDevice, stream);
        hipMemsetAsync(v, 0, BH * 4, stream);
        hipMemsetAsync(out, 0, (size_t)out_size * 4, stream);
        dim3 blkA(256), grdA(HID / 64, BATCH / 64);
        dim3 blkB(256), grdB(DIM / 64, HID / 64);
        for (int t = 0; t < T_STEPS; ++t) {
            const float* xt = x_seq + (size_t)t * BATCH * DIM;
            stdp_fwd_if<<<grdA, blkA, 0, stream>>>(xt, w, v, s, out);
            if (t < T_STEPS - 1) {
                stdp_wupd<<<grdB, blkB, 0, stream>>>(xt, s, w);
            }
        }
    }
}

// Round 20
// 705.620 us; speedup vs baseline: 3.4259x; 3.4259x over previous
//
#include <hip/hip_runtime.h>
#include <hip/hip_bf16.h>

// STDP IF-neuron network, T=50 sequential steps. FINAL = r18 (v15).
// x_seq [50,256,1024] f32, weight [2048,1024] f32 -> trace [256,2048] f32.
//
// Architecture (result of 19 rounds of measurement):
//  - ONE persistent kernel, 128 blocks x 1024 thr (16 waves = 4/SIMD);
//    block owns a 16-h slab for all 50 steps. No inter-block comm
//    (r11/r12/r19 proved every per-step sync scheme costs more than it
//    saves at ~14us step granularity).
//  - W fp32 master + bf16 hi/lo split fragments live in LDS (132 KB);
//    v, trace in registers. Zero W global traffic.
//  - x pre-packed into MFMA-fragment-order streams (r10: 2.04x -- access
//    DENSITY was the dominant wall): XF bf16 hi/lo for fwd, XQ 14-bit
//    fixed-point as two 7-bit i8 digits for wupd (r16: exact integer
//    accumulation via mfma_i32_16x16x64_i8, 2^24-exact recovery).
//  - fwd: 3-product bf16 split compensation (hh+hl+lh), 2-deep pipelined
//    (r17), boundary prefetch across both barriers (r18).
//  - 2 block-local barriers/step.
// Numerics: bit-identical to rounds 16-18 (absmax 1.0 = one +-1 spike
// phase shift, far under threshold). 690us kernel, ~106 GB/s/CU ingest
// = ~85% of the no-reuse per-CU streaming ceiling.

#define T_STEPS 50
#define BATCH   256
#define DIM     1024
#define HID     2048
#define HT      16
#define LR_OVER_B (0.005f / 256.0f)

// LDS: wfs 64KB | whF 32KB | wlF 32KB | slQ 4KB (i8 s frags)
#define SMEM_BYTES (65536 + 32768 + 32768 + 4096)

typedef __attribute__((ext_vector_type(8))) short short8v;
typedef __attribute__((ext_vector_type(4))) float f32x4;
typedef __attribute__((ext_vector_type(4))) int   i32x4;

static __device__ __forceinline__ ushort f32_to_bf16u(float f) {
    __hip_bfloat16 h = __float2bfloat16(f);
    return __builtin_bit_cast(unsigned short, h);
}
static __device__ __forceinline__ float bf16u_to_f32(ushort u) {
    __hip_bfloat16 h = __builtin_bit_cast(__hip_bfloat16, u);
    return __bfloat162float(h);
}

#define MFMA_B16 __builtin_amdgcn_mfma_f32_16x16x32_bf16
#define MFMA_I8  __builtin_amdgcn_mfma_i32_16x16x64_i8

// ---------------- prep A: fwd fragment packing ----------------------------
// XF[t][bt=0..15][c=0..31][h=0..1][lane=0..63][8] ushorts.
__global__ __launch_bounds__(256) void prep_fwd(
    const float* __restrict__ x, ushort* __restrict__ XF)
{
    __shared__ float xs[16 * 1024];
    const int t  = blockIdx.x >> 4;
    const int bt = blockIdx.x & 15;
    const float* xrow = x + ((size_t)t * BATCH + bt * 16) * DIM;
    for (int i = threadIdx.x; i < 16 * 1024 / 4; i += 256)
        ((float4*)xs)[i] = ((const float4*)xrow)[i];
    __syncthreads();

    ushort* outb = XF + ((size_t)t * 16 + bt) * (32 * 2 * 512);
    for (int item = threadIdx.x; item < 32 * 64; item += 256) {
        const int c = item >> 6;
        const int l = item & 63;
        const int row = l & 15;
        const int col = c * 32 + (l >> 4) * 8;
        short8v hv, lv;
#pragma unroll
        for (int j = 0; j < 8; ++j) {
            float v = xs[row * 1024 + col + j];
            ushort h = f32_to_bf16u(v);
            hv[j] = (short)h;
            lv[j] = (short)f32_to_bf16u(v - bf16u_to_f32(h));
        }
        *(short8v*)(outb + ((size_t)c * 2 + 0) * 512 + l * 8) = hv;
        *(short8v*)(outb + ((size_t)c * 2 + 1) * 512 + l * 8) = lv;
    }
}

// ---------------- prep B: wupd i8 fixed-point fragment packing ------------
// XQ[t][dt=0..63][c=0..3][plane hi/lo][lane=0..63][16] bytes.
__global__ __launch_bounds__(256) void prep_xq(
    const float* __restrict__ x, unsigned char* __restrict__ XQ)
{
    __shared__ ushort q14[256 * 16];
    const int t  = blockIdx.x >> 6;
    const int dt = blockIdx.x & 63;
    {
        const int b = threadIdx.x;
        const float* src = x + ((size_t)t * BATCH + b) * DIM + dt * 16;
#pragma unroll
        for (int k = 0; k < 16; ++k) {
            int u = (int)(src[k] * 16384.0f + 0.5f);
            q14[b * 16 + k] = (ushort)(u > 16383 ? 16383 : u);
        }
    }
    __syncthreads();

    unsigned char* outb = XQ + ((size_t)t * 64 + dt) * 8192;
    const int c = threadIdx.x >> 6;      // 0..3
    const int l = threadIdx.x & 63;
    unsigned char hi16[16], lo16[16];
#pragma unroll
    for (int jj = 0; jj < 16; ++jj) {
        const int b2 = c * 64 + (l >> 4) * 16 + jj;
        ushort v = q14[b2 * 16 + (l & 15)];
        hi16[jj] = (unsigned char)(v >> 7);
        lo16[jj] = (unsigned char)(v & 127);
    }
    *(i32x4*)(outb + c * 2048 + l * 16)        = *(i32x4*)hi16;
    *(i32x4*)(outb + c * 2048 + 1024 + l * 16) = *(i32x4*)lo16;
}

// ---------------- THE 16-wave persistent kernel ---------------------------
__global__ __launch_bounds__(1024, 1) void stdp_big(
    const ushort* __restrict__ XF, const unsigned char* __restrict__ XQ,
    const float* __restrict__ weight, float* __restrict__ out)
{
    extern __shared__ char smem[];
    float*  wfs = (float*)smem;               // [64 dt][64 lane][4] fp32 master
    ushort* whF = (ushort*)(smem + 65536);    // 32 chunks x 512 us (frag order)
    ushort* wlF = whF + 32 * 512;
    unsigned char* slQ = (unsigned char*)(smem + 65536 + 32768 + 32768); // 4KB

    const int tid  = threadIdx.x;
    const int lane = tid & 63;
    const int w    = tid >> 6;                // wave 0..15
    const int h0   = blockIdx.x * HT;

    const int fr = lane & 15;                 // h index within slab
    const int rq = (lane >> 4) * 4;           // D-fragment row base

    // ---- init whF/wlF: 32 chunks x 64 lane-slots (2 per thread) ----
    for (int i = tid; i < 32 * 64; i += 1024) {
        const int cc  = i >> 6;
        const int l   = i & 63;
        const int row = l & 15;
        const int col = cc * 32 + (l >> 4) * 8;
        const float* src = &weight[(size_t)(h0 + row) * DIM + col];
        short8v hv, lv;
#pragma unroll
        for (int j = 0; j < 8; ++j) {
            float v = src[j];
            ushort h = f32_to_bf16u(v);
            hv[j] = (short)h;
            lv[j] = (short)f32_to_bf16u(v - bf16u_to_f32(h));
        }
        *(short8v*)&whF[cc * 512 + l * 8] = hv;
        *(short8v*)&wlF[cc * 512 + l * 8] = lv;
    }
    // ---- init wfs: (dt, lane) owns h=lane&15, d=dt*16+((lane>>4)*4)+j ----
    for (int i = tid; i < 64 * 64; i += 1024) {
        const int dt = i >> 6;
        const int l  = i & 63;
        const int h  = l & 15;
        const int d  = dt * 16 + (l >> 4) * 4;
        *(float4*)&wfs[(size_t)i * 4] =
            *(const float4*)&weight[(size_t)(h0 + h) * DIM + d];
    }
    __syncthreads();

    const f32x4 z4 = {0.f, 0.f, 0.f, 0.f};
    const i32x4 zi = {0, 0, 0, 0};
    f32x4 vmem = z4;
    f32x4 trc  = z4;

    short8v GA[2][2], GB[2][2];   // fwd stream buffers (pair = 2 chunks)
    i32x4 FH[4], FL[4];           // wupd tile buffers

#define LDP(F, base, p) do { _Pragma("unroll") \
    for (int c_ = 0; c_ < 2; ++c_) { \
        const int cc_ = (p) * 2 + c_; \
        F[c_][0] = *(const short8v*)((base) + ((size_t)cc_ * 2 + 0) * 512); \
        F[c_][1] = *(const short8v*)((base) + ((size_t)cc_ * 2 + 1) * 512); } } while (0)

#define MFP(F, p) do { _Pragma("unroll") \
    for (int c_ = 0; c_ < 2; ++c_) { \
        const int cc_ = (p) * 2 + c_; \
        short8v bh_ = *(const short8v*)&whF[cc_ * 512 + lane * 8]; \
        short8v bl_ = *(const short8v*)&wlF[cc_ * 512 + lane * 8]; \
        acc = MFMA_B16(F[c_][0], bh_, acc, 0, 0, 0); \
        acc = MFMA_B16(F[c_][0], bl_, acc, 0, 0, 0); \
        acc = MFMA_B16(F[c_][1], bh_, acc, 0, 0, 0); } } while (0)

    // prologue: prefetch fwd pair 0 for t=0
    {
        const ushort* wb0 = XF + (size_t)w * (32 * 2 * 512) + lane * 8;
        LDP(GA, wb0, 0);
    }

    for (int t = 0; t < T_STEPS; ++t) {
        const ushort* wbase = XF + (size_t)t * (16 * 32 * 2 * 512)
                            + (size_t)w * (32 * 2 * 512) + lane * 8;

        // ============ fwd: mem = x @ W^T, 2-deep pipelined ================
        f32x4 acc = z4;
        // GA pair 0 preloaded (prologue or previous iteration's prefetch)
#pragma unroll 1
        for (int it = 0; it < 7; ++it) {
            LDP(GB, wbase, 2 * it + 1);
            MFP(GA, 2 * it);
            LDP(GA, wbase, 2 * it + 2);
            MFP(GB, 2 * it + 1);
        }
        LDP(GB, wbase, 15);
        MFP(GA, 14);
        MFP(GB, 15);

        // ---- IF update + i8 s store (b = w*16 + rq + j, h = fr) ----
        {
            unsigned sword = 0;
#pragma unroll
            for (int j = 0; j < 4; ++j) {
                float nv = vmem[j] + acc[j];
                bool fire = (nv >= 1.0f);
                vmem[j] = fire ? 0.0f : nv;
                trc[j] += fire ? 1.0f : 0.0f;
                sword |= (fire ? 1u : 0u) << (8 * j);
            }
            // slQ layout: chunk c=b>>6, lane l=((b>>4)&3)*16+h, byte jj=b&15
            *(unsigned*)&slQ[(w >> 2) * 1024 + ((w & 3) * 16 + fr) * 16 + rq] = sword;
        }

        if (t >= T_STEPS - 1) break;   // last step: no wupd

        // ---- prefetch wupd tile-0 FH/FL (read-only; overlaps barrier) ----
        const unsigned char* xqt = XQ + (size_t)t * (64 * 8192);
        {
            const unsigned char* tb = xqt + (size_t)(w * 4) * 8192 + lane * 16;
#pragma unroll
            for (int c = 0; c < 4; ++c) {
                FH[c] = *(const i32x4*)(tb + c * 2048);
                FL[c] = *(const i32x4*)(tb + c * 2048 + 1024);
            }
        }

        __syncthreads();               // barrier 1: s complete; W-reads done

        // ============ wupd (i8): dw = s^T x exact int, W += lr/B*dw =======
        // wave w owns d-tiles 4w..4w+3; tile q+1 loads overlap W-update(q).
#pragma unroll
        for (int q = 0; q < 4; ++q) {
            const int dt = w * 4 + q;
            i32x4 aH = zi, aL = zi;
#pragma unroll
            for (int c = 0; c < 4; ++c) {
                i32x4 sf = *(const i32x4*)&slQ[c * 1024 + lane * 16];
                aH = MFMA_I8(FH[c], sf, aH, 0, 0, 0);
                aL = MFMA_I8(FL[c], sf, aL, 0, 0, 0);
            }
            if (q < 3) {               // issue next tile's loads early
                const unsigned char* tb = xqt + (size_t)(dt + 1) * 8192 + lane * 16;
#pragma unroll
                for (int c = 0; c < 4; ++c) {
                    FH[c] = *(const i32x4*)(tb + c * 2048);
                    FL[c] = *(const i32x4*)(tb + c * 2048 + 1024);
                }
            }
            // ---- W master update (LDS, lane-linear) + re-split ----
            {
                float4* wp = (float4*)&wfs[((size_t)dt * 64 + lane) * 4];
                float4 wv = *wp;
                float* wvp = &wv.x;
                ushort4 hi4, lo4;
                ushort* hp = &hi4.x; ushort* lp = &lo4.x;
#pragma unroll
                for (int j = 0; j < 4; ++j) {
                    float du = (float)(aH[j] * 128 + aL[j]) * (1.0f / 16384.0f);
                    float nw = fmaf(LR_OVER_B, du, wvp[j]);
                    wvp[j] = nw;
                    ushort hb = f32_to_bf16u(nw);
                    hp[j] = hb;
                    lp[j] = f32_to_bf16u(nw - bf16u_to_f32(hb));
                }
                *wp = wv;
                const int l_w = fr | (((dt & 1) * 2 + (rq >> 3)) << 4);
                const int off = (dt >> 1) * 512 + l_w * 8 + (rq & 4);
                *(ushort4*)&whF[off] = hi4;
                *(ushort4*)&wlF[off] = lo4;
            }
            __builtin_amdgcn_sched_barrier(0);
        }

        // ---- prefetch fwd pair 0 for t+1 (GA dead here; read-only) ----
        {
            const ushort* wbn = XF + (size_t)(t + 1) * (16 * 32 * 2 * 512)
                              + (size_t)w * (32 * 2 * 512) + lane * 8;
            LDP(GA, wbn, 0);
        }

        __syncthreads();               // barrier 2: whF/wlF ready for next fwd
    }
#undef LDP
#undef MFP

    // ---- write trace (registers) to d_out [B,H]; b = w*16 + rq + j ----
#pragma unroll
    for (int j = 0; j < 4; ++j) {
        const int b = w * 16 + rq + j;
        out[(size_t)b * HID + h0 + fr] = trc[j];
    }
}

// ---------------- fallback fp32 kernels (round-0, small ws) ---------------
#define BK 16
__global__ __launch_bounds__(256) void stdp_fwd_if(
    const float* __restrict__ x, const float* __restrict__ w,
    float* __restrict__ v, float* __restrict__ s, float* __restrict__ trace)
{
    __shared__ float as[BK][64];
    __shared__ float bs[BK][64];
    const int tid = threadIdx.x;
    const int tx = tid & 15, ty = tid >> 4;
    const int b0 = blockIdx.y * 64, h0 = blockIdx.x * 64;
    const int row = tid >> 2, kq = (tid & 3) * 4;
    float acc[4][4] = {};
    for (int k0 = 0; k0 < DIM; k0 += BK) {
        float4 ga = *(const float4*)&x[(size_t)(b0 + row) * DIM + k0 + kq];
        float4 gb = *(const float4*)&w[(size_t)(h0 + row) * DIM + k0 + kq];
        __syncthreads();
        as[kq + 0][row] = ga.x; as[kq + 1][row] = ga.y;
        as[kq + 2][row] = ga.z; as[kq + 3][row] = ga.w;
        bs[kq + 0][row] = gb.x; bs[kq + 1][row] = gb.y;
        bs[kq + 2][row] = gb.z; bs[kq + 3][row] = gb.w;
        __syncthreads();
#pragma unroll
        for (int kk = 0; kk < BK; ++kk) {
            float4 af = *(const float4*)&as[kk][ty * 4];
            float4 bf = *(const float4*)&bs[kk][tx * 4];
            float av[4] = {af.x, af.y, af.z, af.w};
            float bv[4] = {bf.x, bf.y, bf.z, bf.w};
#pragma unroll
            for (int m = 0; m < 4; ++m)
#pragma unroll
                for (int n = 0; n < 4; ++n)
                    acc[m][n] = fmaf(av[m], bv[n], acc[m][n]);
        }
    }
#pragma unroll
    for (int m = 0; m < 4; ++m) {
        size_t idx = (size_t)(b0 + ty * 4 + m) * HID + h0 + tx * 4;
        float4 vv = *(float4*)&v[idx];
        float4 tr = *(float4*)&trace[idx];
        float4 sv;
        float* vvp = &vv.x; float* trp = &tr.x; float* svp = &sv.x;
#pragma unroll
        for (int n = 0; n < 4; ++n) {
            float nv = vvp[n] + acc[m][n];
            float sp = (nv >= 1.0f) ? 1.0f : 0.0f;
            vvp[n] = (nv >= 1.0f) ? 0.0f : nv;
            svp[n] = sp; trp[n] += sp;
        }
        *(float4*)&v[idx] = vv;
        *(float4*)&s[idx] = sv;
        *(float4*)&trace[idx] = tr;
    }
}

__global__ __launch_bounds__(256) void stdp_wupd(
    const float* __restrict__ x, const float* __restrict__ s,
    float* __restrict__ w)
{
    __shared__ float ss[BK][64];
    __shared__ float xs[BK][64];
    const int tid = threadIdx.x;
    const int tx = tid & 15, ty = tid >> 4;
    const int h0 = blockIdx.y * 64, d0 = blockIdx.x * 64;
    const int krow = tid >> 4, c4 = (tid & 15) * 4;
    float acc[4][4] = {};
    for (int bk0 = 0; bk0 < BATCH; bk0 += BK) {
        float4 gs = *(const float4*)&s[(size_t)(bk0 + krow) * HID + h0 + c4];
        float4 gx = *(const float4*)&x[(size_t)(bk0 + krow) * DIM + d0 + c4];
        __syncthreads();
        *(float4*)&ss[krow][c4] = gs;
        *(float4*)&xs[krow][c4] = gx;
        __syncthreads();
#pragma unroll
        for (int kk = 0; kk < BK; ++kk) {
            float4 af = *(const float4*)&ss[kk][ty * 4];
            float4 bf = *(const float4*)&xs[kk][tx * 4];
            float av[4] = {af.x, af.y, af.z, af.w};
            float bv[4] = {bf.x, bf.y, bf.z, bf.w};
#pragma unroll
            for (int m = 0; m < 4; ++m)
#pragma unroll
                for (int n = 0; n < 4; ++n)
                    acc[m][n] = fmaf(av[m], bv[n], acc[m][n]);
        }
    }
#pragma unroll
    for (int m = 0; m < 4; ++m) {
        size_t idx = (size_t)(h0 + ty * 4 + m) * DIM + d0 + tx * 4;
        float4 wv = *(float4*)&w[idx];
        wv.x = fmaf(LR_OVER_B, acc[m][0], wv.x);
        wv.y = fmaf(LR_OVER_B, acc[m][1], wv.y);
        wv.z = fmaf(LR_OVER_B, acc[m][2], wv.z);
        wv.w = fmaf(LR_OVER_B, acc[m][3], wv.w);
        *(float4*)&w[idx] = wv;
    }
}

extern "C" void kernel_launch(void* const* d_in, const int* in_sizes, int n_in,
                              void* d_out, int out_size, void* d_ws, size_t ws_size,
                              hipStream_t stream) {
    (void)in_sizes; (void)n_in;
    const float* x_seq  = (const float*)d_in[0];   // [T, B, D]
    const float* weight = (const float*)d_in[1];   // [H, D]
    float* out = (float*)d_out;                    // [B, H]

    const size_t WN = (size_t)HID * DIM;
    const size_t BH = (size_t)BATCH * HID;
    const size_t XN = (size_t)T_STEPS * BATCH * DIM;  // 13107200

    // ws: XF (4*XN bytes) | XQ (2*XN bytes)
    const size_t need = 6 * XN;

    if (ws_size >= need) {
        ushort* XF = (ushort*)d_ws;                   // 2*XN ushorts
        unsigned char* XQ = (unsigned char*)(XF + 2 * XN);

        prep_fwd<<<T_STEPS * 16, 256, 0, stream>>>(x_seq, XF);
        prep_xq<<<T_STEPS * 64, 256, 0, stream>>>(x_seq, XQ);

        hipFuncSetAttribute(reinterpret_cast<const void*>(&stdp_big),
                            hipFuncAttributeMaxDynamicSharedMemorySize,
                            SMEM_BYTES);
        stdp_big<<<HID / HT, 1024, SMEM_BYTES, stream>>>(
            XF, XQ, weight, out);
    } else {
        // fallback: fp32 VALU path (needs ~12.6 MB)
        float* w = (float*)d_ws;
        float* v = w + WN;
        float* s = v + BH;
        hipMemcpyAsync(w, weight, WN * 4, hipMemcpyDeviceToDevice, stream);
        hipMemsetAsync(v, 0, BH * 4, stream);
        hipMemsetAsync(out, 0, (size_t)out_size * 4, stream);
        dim3 blkA(256), grdA(HID / 64, BATCH / 64);
        dim3 blkB(256), grdB(DIM / 64, HID / 64);
        for (int t = 0; t < T_STEPS; ++t) {
            const float* xt = x_seq + (size_t)t * BATCH * DIM;
            stdp_fwd_if<<<grdA, blkA, 0, stream>>>(xt, w, v, s, out);
            if (t < T_STEPS - 1) {
                stdp_wupd<<<grdB, blkB, 0, stream>>>(xt, s, w);
            }
        }
    }
}